// Round 10
// baseline (1196.646 us; speedup 1.0000x reference)
//
#include <hip/hip_runtime.h>
#include <hip/hip_bf16.h>

typedef __hip_bfloat16 bf16;
typedef unsigned short u16;
typedef unsigned int u32;
typedef unsigned long long u64;
typedef __attribute__((ext_vector_type(8))) short s16x8;
typedef __attribute__((ext_vector_type(4))) float f32x4;

#define NN 500000
#define EE 2000000
#define GG 256
#define NB_SCAN 489  // ceil(500000/1024); also bucket count (1024-node ranges)
#define BCHUNK 1024  // edges per binA block
#define LCAP 16      // LDS bin capacity (mean 2.09/bin/chunk)
#define GCAP 8192    // global bucket capacity (mean 4090, ~64 sigma)
#define OVFCAP 8192  // overflow list capacity
#define CAPB 6144    // sortB LDS staging capacity (mean 4090, ~32 sigma)

// weight bank offsets (floats)
#define WREL1 0
#define BREL1 16
#define WROOT1 32
#define WREL2 48
#define BREL2 560
#define WROOT2 592
#define WREL3 1104
#define BREL3 3152
#define WROOT3 3216
#define WRELMU 5264
#define BRELMU 9360
#define WROOTMU 9424
#define WRELLV 13520
#define BRELLV 17616
#define WROOTLV 17680
#define GNW 21776
#define GNB 21840
#define GNMS 21904

__device__ __forceinline__ float b2f(u16 u) {
  union { u32 i; float f; } cv; cv.i = ((u32)u) << 16; return cv.f;
}
__device__ __forceinline__ u16 f2b(float f) {
  union { bf16 b; u16 u; } cv; cv.b = __float2bfloat16(f); return cv.u;
}
__device__ __forceinline__ float loadF(const void* p, size_t i, int isbf) {
  if (isbf) return b2f(((const u16*)p)[i]);
  return ((const float*)p)[i];
}
__device__ __forceinline__ int loadI(const void* p, size_t i, int is64) {
  if (is64) return (int)(((const long long*)p)[i]);
  return ((const int*)p)[i];
}

__global__ void probe_k(const void* ew, const void* ei, const void* batch,
                        int* __restrict__ flags) {
  if (threadIdx.x != 0 || blockIdx.x != 0) return;
  const u32* u = (const u32*)ew;
  int hits = 0;
  for (int i = 0; i < 64; ++i) {
    u32 b1 = (u[i] >> 8) & 0xFF;
    if (b1 >= 0x30 && b1 <= 0x3F) hits++;
  }
  flags[0] = (hits >= 32) ? 1 : 0;  // floats are bf16
  const int* w = (const int*)ei;
  int nz = 0;
  for (int i = 1; i < 512; i += 2) nz += (w[i] != 0);
  flags[1] = (nz == 0) ? 1 : 0;  // edge_index int64
  const int* b = (const int*)batch;
  int nzb = 0;
  for (int k = 0; k < 64; ++k) nzb += (b[NN - 1 - 2 * k] != 0);
  flags[2] = (nzb == 0) ? 1 : 0;  // batch int64
}

struct WArg { const void* p[18]; int sz[18]; int off[18]; };

__global__ void cvt_weights(WArg a, float* __restrict__ out, const int* __restrict__ flg) {
  int fb = flg[0];
  int b = blockIdx.x;
  const void* src = a.p[b];
  float* dst = out + a.off[b];
  int n = a.sz[b];
  for (int i = threadIdx.x; i < n; i += blockDim.x) dst[i] = loadF(src, i, fb);
}

// pack weights into MFMA B-fragment order (+ bias vectors), per layer
__global__ void pack_w(const float* __restrict__ wb, u16* __restrict__ wp2,
                       u16* __restrict__ wp3, u16* __restrict__ wpF,
                       float* __restrict__ b2, float* __restrict__ b3,
                       float* __restrict__ bF) {
  int L = blockIdx.x;
  int K = (L == 0) ? 32 : (L == 1) ? 64 : 128;
  int COUT = K;
  int KS = K / 32;
  u16* wp = (L == 0) ? wp2 : (L == 1) ? wp3 : wpF;
  int total = K * COUT;
  for (int idx = threadIdx.x; idx < total; idx += blockDim.x) {
    int j = idx & 7;
    int l = (idx >> 3) & 63;
    int rest = idx >> 9;
    int s = rest % KS;
    int t = rest / KS;
    int k = s * 32 + (l >> 4) * 8 + j;
    int c = t * 16 + (l & 15);
    float v;
    if (L == 0) {
      v = (k < 16) ? wb[WREL2 + k * 32 + c] : wb[WROOT2 + (k - 16) * 32 + c];
    } else if (L == 1) {
      v = (k < 32) ? wb[WREL3 + k * 64 + c] : wb[WROOT3 + (k - 32) * 64 + c];
    } else {
      int cc = c & 63;
      int base;
      if (k < 64) base = (c < 64) ? WRELMU : WRELLV;
      else base = (c < 64) ? WROOTMU : WROOTLV;
      int kk = (k < 64) ? k : (k - 64);
      v = wb[base + kk * 64 + cc];
    }
    wp[idx] = f2b(v);
  }
  for (int c = threadIdx.x; c < COUT; c += blockDim.x) {
    if (L == 0) b2[c] = wb[BREL2 + c];
    else if (L == 1) b3[c] = wb[BREL3 + c];
    else bF[c] = (c < 64) ? wb[BRELMU + c] : wb[BRELLV + (c - 64)];
  }
}

__global__ void seg_offsets(const void* __restrict__ batch, int* __restrict__ goffs,
                            const int* __restrict__ flg) {
  int f64 = flg[2];
  int g = blockIdx.x * blockDim.x + threadIdx.x;
  if (g > GG) return;
  int lo = 0, hi = NN;
  while (lo < hi) {
    int mid = (lo + hi) >> 1;
    if (loadI(batch, mid, f64) < g) lo = mid + 1; else hi = mid;
  }
  goffs[g] = lo;
}

// ---------------- CSR build: LDS-binned bucket pass + counting-sort pass ----------------
__global__ __launch_bounds__(256) void binA_k(
    const void* __restrict__ ei, const void* __restrict__ ew,
    int* __restrict__ counts, int* __restrict__ gbcnt, u64* __restrict__ gbucket,
    int* __restrict__ ovf_cnt, int* __restrict__ ovf_bin, u64* __restrict__ ovf_pay,
    const int* __restrict__ flg) {
  __shared__ u64 bins[NB_SCAN][LCAP];
  __shared__ int bcnt[NB_SCAN];
  int fi = flg[1], fb = flg[0];
  int tid = threadIdx.x;
  for (int i = tid; i < NB_SCAN; i += 256) bcnt[i] = 0;
  __syncthreads();
  int base = blockIdx.x * BCHUNK;
#pragma unroll
  for (int k = 0; k < BCHUNK / 256; ++k) {
    int e = base + k * 256 + tid;
    if (e < EE) {
      int s = loadI(ei, e, fi);
      int d = loadI(ei, (size_t)EE + e, fi);
      float w = loadF(ew, e, fb);
      atomicAdd(&counts[d], 1);
      int b = d >> 10;
      u64 pay = (u64)((u32)s | ((u32)(d & 1023) << 19));
      pay |= ((u64)__float_as_uint(w)) << 32;
      int l = atomicAdd(&bcnt[b], 1);
      if (l < LCAP) bins[b][l] = pay;
      else {
        int o = atomicAdd(ovf_cnt, 1);
        if (o < OVFCAP) { ovf_bin[o] = b; ovf_pay[o] = pay; }
      }
    }
  }
  __syncthreads();
  for (int b = tid; b < NB_SCAN; b += 256) {
    int c = bcnt[b];
    if (c > LCAP) c = LCAP;
    if (c > 0) {
      int gb = atomicAdd(&gbcnt[b * 16], c);
      for (int i = 0; i < c; ++i) {
        int pos = gb + i;
        if (pos < GCAP) gbucket[(size_t)b * GCAP + pos] = bins[b][i];
        else {
          int o = atomicAdd(ovf_cnt, 1);
          if (o < OVFCAP) { ovf_bin[o] = b; ovf_pay[o] = bins[b][i]; }
        }
      }
    }
  }
}

__global__ void scan1_k(const int* __restrict__ counts, int* __restrict__ chunkscan,
                        int* __restrict__ bsum) {
  __shared__ int lds[256];
  int b = blockIdx.x, t = threadIdx.x;
  int base = b * 1024 + t * 4;
  int c0 = 0, c1 = 0, c2 = 0, c3 = 0;
  if (base + 3 < NN) {
    int4 c = *(const int4*)(counts + base);
    c0 = c.x; c1 = c.y; c2 = c.z; c3 = c.w;
  } else {
    if (base + 0 < NN) c0 = counts[base + 0];
    if (base + 1 < NN) c1 = counts[base + 1];
    if (base + 2 < NN) c2 = counts[base + 2];
    if (base + 3 < NN) c3 = counts[base + 3];
  }
  int s0 = c0, s1 = s0 + c1, s2 = s1 + c2, s3 = s2 + c3;
  lds[t] = s3;
  __syncthreads();
  for (int off = 1; off < 256; off <<= 1) {
    int v = lds[t];
    if (t >= off) v += lds[t - off];
    __syncthreads();
    lds[t] = v;
    __syncthreads();
  }
  int excl = (t > 0) ? lds[t - 1] : 0;
  if (base + 0 < NN) chunkscan[base + 0] = excl + s0;
  if (base + 1 < NN) chunkscan[base + 1] = excl + s1;
  if (base + 2 < NN) chunkscan[base + 2] = excl + s2;
  if (base + 3 < NN) chunkscan[base + 3] = excl + s3;
  if (t == 255) bsum[b] = lds[255];
}

__global__ void scan2_k(int* __restrict__ bsum) {
  __shared__ int lds[512];
  int t = threadIdx.x;
  int v = (t < NB_SCAN) ? bsum[t] : 0;
  lds[t] = v;
  __syncthreads();
  for (int off = 1; off < 512; off <<= 1) {
    int x = lds[t];
    if (t >= off) x += lds[t - off];
    __syncthreads();
    lds[t] = x;
    __syncthreads();
  }
  if (t < NB_SCAN) bsum[t] = lds[t] - v;  // exclusive
}

__global__ void scan3_k(const int* __restrict__ chunkscan, const int* __restrict__ bsum,
                        const int* __restrict__ counts, int* __restrict__ offs) {
  int i = blockIdx.x * blockDim.x + threadIdx.x;
  if (i >= NN) return;
  int pref = chunkscan[i] + bsum[i >> 10];
  offs[i + 1] = pref;
  if (i == 0) offs[0] = 0;
}

// pass B: one block per bucket; LDS counting sort by dst, stream cw out coalesced.
__global__ __launch_bounds__(256) void sortB_k(
    const u64* __restrict__ gbucket, const int* __restrict__ gbcnt,
    const int* __restrict__ ovf_cnt, const int* __restrict__ ovf_bin,
    const u64* __restrict__ ovf_pay, const int* __restrict__ offs,
    int2* __restrict__ cw) {
  __shared__ u64 sorted[CAPB];
  __shared__ int lcnt[1024];
  __shared__ int lcur[1024];
  __shared__ int pscan[256];
  __shared__ int stot;
  int b = blockIdx.x, tid = threadIdx.x;
  int r0 = b << 10;
  int cnt = gbcnt[b * 16];
  if (cnt > GCAP) cnt = GCAP;
  int ovn = *ovf_cnt;
  if (ovn > OVFCAP) ovn = OVFCAP;
  for (int i = tid; i < 1024; i += 256) lcnt[i] = 0;
  __syncthreads();
  for (int i = tid; i < cnt; i += 256) {
    u32 p = (u32)gbucket[(size_t)b * GCAP + i];
    atomicAdd(&lcnt[p >> 19], 1);
  }
  for (int i = tid; i < ovn; i += 256)
    if (ovf_bin[i] == b) atomicAdd(&lcnt[(u32)ovf_pay[i] >> 19], 1);
  __syncthreads();
  int t4 = tid * 4;
  int s0 = lcnt[t4], s1 = lcnt[t4 + 1], s2 = lcnt[t4 + 2], s3 = lcnt[t4 + 3];
  int tsum = s0 + s1 + s2 + s3;
  pscan[tid] = tsum;
  __syncthreads();
  for (int off = 1; off < 256; off <<= 1) {
    int v = pscan[tid];
    int vv = (tid >= off) ? pscan[tid - off] : 0;
    __syncthreads();
    pscan[tid] = v + vv;
    __syncthreads();
  }
  int excl = (tid > 0) ? pscan[tid - 1] : 0;
  lcur[t4] = excl;
  lcur[t4 + 1] = excl + s0;
  lcur[t4 + 2] = excl + s0 + s1;
  lcur[t4 + 3] = excl + s0 + s1 + s2;
  if (tid == 255) stot = pscan[255];
  __syncthreads();
  int total = stot;
  bool stage = (total <= CAPB);
  long gbase = offs[r0];
  for (int i = tid; i < cnt; i += 256) {
    u64 pay = gbucket[(size_t)b * GCAP + i];
    u32 p = (u32)pay;
    int pos = atomicAdd(&lcur[p >> 19], 1);
    if (stage) sorted[pos] = pay;
    else cw[gbase + pos] = make_int2((int)(p & 0x7FFFF), (int)(pay >> 32));
  }
  for (int i = tid; i < ovn; i += 256) {
    if (ovf_bin[i] != b) continue;
    u64 pay = ovf_pay[i];
    u32 p = (u32)pay;
    int pos = atomicAdd(&lcur[p >> 19], 1);
    if (stage) sorted[pos] = pay;
    else cw[gbase + pos] = make_int2((int)(p & 0x7FFFF), (int)(pay >> 32));
  }
  __syncthreads();
  if (stage) {
    for (int i = tid; i < total; i += 256) {
      u64 pay = sorted[i];
      u32 p = (u32)pay;
      cw[gbase + i] = make_int2((int)(p & 0x7FFFF), (int)(pay >> 32));
    }
  }
}

// ---------------- conv1 (fused agg + transform, C_in=1 -> 16) ----------------
__global__ void conv1_k(const void* __restrict__ x, const int2* __restrict__ cw,
                        const int* __restrict__ offs, const float* __restrict__ wb,
                        u16* __restrict__ h1, const int* __restrict__ flg) {
  int fb = flg[0];
  int n = blockIdx.x * blockDim.x + threadIdx.x;
  if (n >= NN) return;
  float acc = 0.f;
  int j1 = offs[n + 1];
  for (int j = offs[n]; j < j1; ++j) {
    int2 p = cw[j];
    acc += __int_as_float(p.y) * loadF(x, p.x, fb);
  }
  float xx = loadF(x, n, fb);
  u32 pk[8];
#pragma unroll
  for (int p = 0; p < 8; ++p) {
    float v0 = fmaxf(acc * wb[WREL1 + 2 * p] + wb[BREL1 + 2 * p] + xx * wb[WROOT1 + 2 * p], 0.f);
    float v1 = fmaxf(acc * wb[WREL1 + 2 * p + 1] + wb[BREL1 + 2 * p + 1] + xx * wb[WROOT1 + 2 * p + 1], 0.f);
    pk[p] = (u32)f2b(v0) | ((u32)f2b(v1) << 16);
  }
  uint4* dst = (uint4*)(h1 + (size_t)n * 16);
  dst[0] = make_uint4(pk[0], pk[1], pk[2], pk[3]);
  dst[1] = make_uint4(pk[4], pk[5], pk[6], pk[7]);
}

// ---------------- fused gather + MFMA node transform ----------------
// Work-stealing: each wave grabs ADJACENT tile pairs via a global counter
// (fixes tail imbalance from degree variance; adjacent tiles share offs/cw lines).
template <int K, int COUT, bool RELU, bool FINAL>
__global__ __launch_bounds__(256) void fused_conv(
    const u16* __restrict__ hin, const int2* __restrict__ cw,
    const int* __restrict__ offs, const u16* __restrict__ wpack,
    const float* __restrict__ bias, void* __restrict__ outp,
    const int* __restrict__ flg, int* __restrict__ wctr) {
  constexpr int KS = K / 32, CT = COUT / 16, CIN = K / 2;
  constexpr int AS = CIN / 32;               // pure-agg slices
  constexpr bool MIX = (CIN % 32) == 16;     // mixed slice exists (conv2 only)
  constexpr int GA = AS + (MIX ? 1 : 0);
  constexpr int ST_LD = COUT + 8;            // staging row stride (u16), bank-skewed
  __shared__ u16 wl[K * COUT];
  __shared__ float bl[COUT];
  __shared__ u16 stbuf[FINAL ? 4 : 4 * 16 * ST_LD];
  int tid = threadIdx.x;
  for (int i = tid; i < K * COUT / 8; i += 256)
    ((uint4*)wl)[i] = ((const uint4*)wpack)[i];
  for (int i = tid; i < COUT; i += 256) bl[i] = bias[i];
  __syncthreads();
  int fb = FINAL ? flg[0] : 1;
  int lane = tid & 63, wave = tid >> 6;
  int q = lane & 15, kgrp = lane >> 4;
  u16* st = FINAL ? stbuf : (stbuf + wave * 16 * ST_LD);
  const int ntiles = NN / 16;
  while (true) {
    int pos;
    if (lane == 0) pos = atomicAdd(wctr, 2);
    pos = __shfl(pos, 0);
    if (pos >= ntiles) break;
    int t0 = pos;
    int t1 = pos + 1;
    bool has1 = (t1 < ntiles);
    int nA = t0 * 16 + q;
    int nB = has1 ? (t1 * 16 + q) : nA;
    int jbA = offs[nA], jeA = offs[nA + 1];
    int jbB = 0, jeB = 0;
    if (has1) { jbB = offs[nB]; jeB = offs[nB + 1]; }
    float gacc[2][GA][8];
#pragma unroll
    for (int tt = 0; tt < 2; ++tt)
#pragma unroll
      for (int s = 0; s < GA; ++s)
#pragma unroll
        for (int jj = 0; jj < 8; ++jj) gacc[tt][s][jj] = 0.f;
    int lA = jeA - jbA, lB = jeB - jbB;
    int iters = max((lA + 1) >> 1, (lB + 1) >> 1);
    for (int it = 0; it < iters; ++it) {
      int2 pp[4];
      float ww[4];
      int j0 = jbA + 2 * it, j1 = j0 + 1;
      int j2 = jbB + 2 * it, j3 = j2 + 1;
      int jc0 = j0 < EE ? j0 : EE - 1;
      int jc1 = j1 < EE ? j1 : EE - 1;
      int jc2 = j2 < EE ? j2 : EE - 1;
      int jc3 = j3 < EE ? j3 : EE - 1;
      pp[0] = cw[jc0]; pp[1] = cw[jc1]; pp[2] = cw[jc2]; pp[3] = cw[jc3];
      ww[0] = (j0 < jeA) ? __int_as_float(pp[0].y) : 0.f;
      ww[1] = (j1 < jeA) ? __int_as_float(pp[1].y) : 0.f;
      ww[2] = (j2 < jeB) ? __int_as_float(pp[2].y) : 0.f;
      ww[3] = (j3 < jeB) ? __int_as_float(pp[3].y) : 0.f;
      s16x8 vv[4][GA];
#pragma unroll
      for (int sl = 0; sl < 4; ++sl) {
        const u16* rr = hin + (size_t)pp[sl].x * CIN;
#pragma unroll
        for (int s = 0; s < AS; ++s)
          vv[sl][s] = *(const s16x8*)(rr + s * 32 + kgrp * 8);
        if (MIX && kgrp < 2)
          vv[sl][AS] = *(const s16x8*)(rr + kgrp * 8);
      }
#pragma unroll
      for (int sl = 0; sl < 4; ++sl) {
#pragma unroll
        for (int s = 0; s < AS; ++s)
#pragma unroll
          for (int jj = 0; jj < 8; ++jj)
            gacc[sl >> 1][s][jj] += ww[sl] * b2f((u16)vv[sl][s][jj]);
        if (MIX && kgrp < 2)
#pragma unroll
          for (int jj = 0; jj < 8; ++jj)
            gacc[sl >> 1][AS][jj] += ww[sl] * b2f((u16)vv[sl][AS][jj]);
      }
    }
#pragma unroll
    for (int tt = 0; tt < 2; ++tt) {
      if (tt == 1 && !has1) break;
      int n0 = (tt == 0 ? t0 : t1) * 16;
      int n = n0 + q;
      s16x8 a[KS];
#pragma unroll
      for (int s = 0; s < KS; ++s) {
        if (s < AS) {
          s16x8 t;
#pragma unroll
          for (int jj = 0; jj < 8; ++jj) t[jj] = (short)f2b(gacc[tt][s][jj]);
          a[s] = t;
        } else if (MIX && s == AS) {
          if (kgrp < 2) {
            s16x8 t;
#pragma unroll
            for (int jj = 0; jj < 8; ++jj) t[jj] = (short)f2b(gacc[tt][AS][jj]);
            a[s] = t;
          } else {
            a[s] = *(const s16x8*)(hin + (size_t)n * CIN + (kgrp * 8 - 16));
          }
        } else {
          a[s] = *(const s16x8*)(hin + (size_t)n * CIN + (s * 32 + kgrp * 8 - CIN));
        }
      }
      f32x4 acc[CT];
#pragma unroll
      for (int t = 0; t < CT; ++t) {
        float bv = bl[t * 16 + q];
        acc[t] = (f32x4){bv, bv, bv, bv};
      }
#pragma unroll
      for (int s = 0; s < KS; ++s) {
#pragma unroll
        for (int t = 0; t < CT; ++t) {
          s16x8 b = *(const s16x8*)(wl + ((size_t)(t * KS + s) * 64 + lane) * 8);
          acc[t] = __builtin_amdgcn_mfma_f32_16x16x32_bf16(a[s], b, acc[t], 0, 0, 0);
        }
      }
      if (!FINAL) {
#pragma unroll
        for (int t = 0; t < CT; ++t) {
          int cc = t * 16 + q;
#pragma unroll
          for (int r = 0; r < 4; ++r) {
            float v = acc[t][r];
            if (RELU) v = fmaxf(v, 0.f);
            st[(kgrp * 4 + r) * ST_LD + cc] = f2b(v);
          }
        }
        constexpr int LPR = COUT / 8;
        constexpr int PASSES = 16 * LPR / 64;
        u16* out = (u16*)outp;
#pragma unroll
        for (int p = 0; p < PASSES; ++p) {
          int idx = p * 64 + lane;
          int row = idx / LPR, seg = idx % LPR;
          *(uint4*)(out + (size_t)(n0 + row) * COUT + seg * 8) =
              *(const uint4*)(st + row * ST_LD + seg * 8);
        }
      } else {
#pragma unroll
        for (int t = 0; t < CT; ++t) {
          int c = t * 16 + q;
#pragma unroll
          for (int r = 0; r < 4; ++r) {
            int nn = n0 + kgrp * 4 + r;
            float v = acc[t][r];
            size_t addr = (t < 4) ? ((size_t)nn * 64 + c)
                                  : ((size_t)NN * 64 + (size_t)nn * 64 + (c - 64));
            if (fb) ((u16*)outp)[addr] = f2b(v);
            else ((float*)outp)[addr] = v;
          }
        }
      }
    }
  }
}

// ---------------- GraphNorm, 2-pass (sum+sumsq fused), H3 -> H3n ----------------
__global__ void graphnorm2(const u16* __restrict__ h, u16* __restrict__ hn,
                           const int* __restrict__ goffs, const float* __restrict__ wb) {
  __shared__ float red[1024];
  __shared__ float red2[1024];
  __shared__ float Ax[64];
  __shared__ float Bx[64];
  int g = blockIdx.x;
  int s = goffs[g], e = goffs[g + 1];
  int len = e - s;
  if (len <= 0) return;
  long base = (long)s * 64, end = (long)e * 64;
  int t = threadIdx.x;
  int c = t & 63;

  float ls = 0.f, lq = 0.f;
  for (long i = base + t; i < end; i += 1024) {
    float v = b2f(h[i]);
    ls += v; lq += v * v;
  }
  red[t] = ls; red2[t] = lq;
  __syncthreads();
  if (t < 64) {
    float S = 0.f, Q = 0.f;
#pragma unroll
    for (int j = 0; j < 16; ++j) { S += red[t + 64 * j]; Q += red2[t + 64 * j]; }
    float mean = S / (float)len;
    float ex2 = Q / (float)len;
    float mms = mean * wb[GNMS + t];
    float var = ex2 - 2.f * mms * mean + mms * mms;
    float a = wb[GNW + t] * rsqrtf(var + 1e-5f);
    Ax[t] = a;
    Bx[t] = wb[GNB + t] - mms * a;
  }
  __syncthreads();
  for (long i = base + t; i < end; i += 1024)
    hn[i] = f2b(b2f(h[i]) * Ax[c] + Bx[c]);
}

extern "C" void kernel_launch(void* const* d_in, const int* in_sizes, int n_in,
                              void* d_out, int out_size, void* d_ws, size_t ws_size,
                              hipStream_t stream) {
  const void* x = d_in[0];
  const void* ei = d_in[1];
  const void* ew = d_in[2];
  const void* batch = d_in[3];

  char* ws = (char*)d_ws;
  // Layout (bytes):
  //  H3      [0, 64e6)        bf16 N*64 (conv3 output, pre-norm)
  //  cw      [64e6, 80e6)     int2 E (col, wgt-bits), dst-sorted CSR payload
  //  offs    [80e6, +2.000004e6)
  //  counts  [83e6, +2e6)  bsum [87e6, +4KB)
  //  wb      [87.1e6, +88KB)  goffs [87.25e6, +1028B)  flags [87.3e6, +16B)
  //  wp2     [87.35e6, +2KB)  wp3 [87.4e6, +8KB)  wpF [87.45e6, +32KB)
  //  bias2   [87.5e6) bias3 [87.51e6) biasF [87.52e6)
  //  gbcnt   [87.53e6, +31300B)  wctr [87.57e6, +64B)
  //  ovf_pay [87.60e6, +64KB)  ovf_bin [87.67e6, +32KB)
  //  C = [88e6, 256e6), time-shared:
  //    gbucket u64 489*8192 @C+0   [88e6, 120.05e6)  (CSR build only)
  //    chunkscan @C+33e6 (2MB)                        (CSR build only)
  //    h1   bf16 N*16 @C+0     [88e6, 104e6)   (written by conv1, after CSR)
  //    h2   bf16 N*32 @C+32e6  [120e6, 152e6)  (written by conv2, after CSR)
  //    H3n  bf16 N*64 @C+96e6  [184e6, 248e6)  (normalized)
  u16* H3 = (u16*)(ws);
  int2* cw = (int2*)(ws + 64000000);
  int* offs = (int*)(ws + 80000000);
  int* counts = (int*)(ws + 83000000);
  int* bsum = (int*)(ws + 87000000);
  float* wb = (float*)(ws + 87100000);
  int* goffs = (int*)(ws + 87250000);
  int* flags = (int*)(ws + 87300000);
  u16* wp2 = (u16*)(ws + 87350000);
  u16* wp3 = (u16*)(ws + 87400000);
  u16* wpF = (u16*)(ws + 87450000);
  float* bias2 = (float*)(ws + 87500000);
  float* bias3 = (float*)(ws + 87510000);
  float* biasF = (float*)(ws + 87520000);
  int* gbcnt = (int*)(ws + 87530000);
  int* ovf_cnt = gbcnt + NB_SCAN * 16;
  int* wctr = (int*)(ws + 87570000);
  u64* ovf_pay = (u64*)(ws + 87600000);
  int* ovf_bin = (int*)(ws + 87670000);
  char* C = ws + 88000000;
  u64* gbucket = (u64*)(C);
  int* chunkscan = (int*)(C + 33000000);
  u16* h1 = (u16*)(C);
  u16* h2 = (u16*)(C + 32000000);
  u16* H3n = (u16*)(C + 96000000);

  WArg wa;
  const int wsz[18] = {16, 16, 16, 512, 32, 512, 2048, 64, 2048,
                       4096, 64, 4096, 4096, 64, 4096, 64, 64, 64};
  const int woff[18] = {WREL1, BREL1, WROOT1, WREL2, BREL2, WROOT2,
                        WREL3, BREL3, WROOT3, WRELMU, BRELMU, WROOTMU,
                        WRELLV, BRELLV, WROOTLV, GNW, GNB, GNMS};
  for (int i = 0; i < 18; ++i) { wa.p[i] = d_in[4 + i]; wa.sz[i] = wsz[i]; wa.off[i] = woff[i]; }

  probe_k<<<1, 64, 0, stream>>>(ew, ei, batch, flags);
  cvt_weights<<<18, 256, 0, stream>>>(wa, wb, flags);
  pack_w<<<3, 256, 0, stream>>>(wb, wp2, wp3, wpF, bias2, bias3, biasF);
  seg_offsets<<<2, 256, 0, stream>>>(batch, goffs, flags);

  // CSR build: bin -> scan -> counting-sort (R8 known-good)
  hipMemsetAsync(counts, 0, (size_t)NN * sizeof(int), stream);
  hipMemsetAsync(gbcnt, 0, (size_t)(NB_SCAN * 16 + 1) * sizeof(int), stream);
  hipMemsetAsync(wctr, 0, 64, stream);
  binA_k<<<(EE + BCHUNK - 1) / BCHUNK, 256, 0, stream>>>(
      ei, ew, counts, gbcnt, gbucket, ovf_cnt, ovf_bin, ovf_pay, flags);
  scan1_k<<<NB_SCAN, 256, 0, stream>>>(counts, chunkscan, bsum);
  scan2_k<<<1, 512, 0, stream>>>(bsum);
  scan3_k<<<(NN + 255) / 256, 256, 0, stream>>>(chunkscan, bsum, counts, offs);
  sortB_k<<<NB_SCAN, 256, 0, stream>>>(gbucket, gbcnt, ovf_cnt, ovf_bin, ovf_pay,
                                       offs, cw);

  // conv1: 1 -> 16
  conv1_k<<<(NN + 255) / 256, 256, 0, stream>>>(x, cw, offs, wb, h1, flags);

  // conv2: 16 -> 32 (K=32), gather fused, work-stealing
  fused_conv<32, 32, true, false><<<2048, 256, 0, stream>>>(
      h1, cw, offs, wp2, bias2, h2, flags, wctr + 0);

  // conv3: 32 -> 64 (K=64), gather fused, work-stealing
  fused_conv<64, 64, true, false><<<2048, 256, 0, stream>>>(
      h2, cw, offs, wp3, bias3, H3, flags, wctr + 4);

  // GraphNorm: H3 -> H3n (2-pass)
  graphnorm2<<<GG, 1024, 0, stream>>>(H3, H3n, goffs, wb);

  // mu + logvar (K=128, COUT=128), gather fused, work-stealing
  fused_conv<128, 128, false, true><<<2048, 256, 0, stream>>>(
      H3n, cw, offs, wpF, biasF, d_out, flags, wctr + 8);
}

// Round 11
// 460.514 us; speedup vs baseline: 2.5985x; 2.5985x over previous
//
#include <hip/hip_runtime.h>
#include <hip/hip_bf16.h>

typedef __hip_bfloat16 bf16;
typedef unsigned short u16;
typedef unsigned int u32;
typedef unsigned long long u64;
typedef __attribute__((ext_vector_type(8))) short s16x8;
typedef __attribute__((ext_vector_type(4))) float f32x4;

#define NN 500000
#define EE 2000000
#define GG 256
#define NB_SCAN 489  // ceil(500000/1024); bucket count (1024-node ranges)
#define BCHUNK 4096  // edges per binA3 block
#define GCAP 8192    // global bucket capacity (mean 4090, ~64 sigma)
#define CAPB 6144    // sortB4 LDS staging capacity (mean 4090, ~32 sigma)

// weight bank offsets (floats)
#define WREL1 0
#define BREL1 16
#define WROOT1 32
#define WREL2 48
#define BREL2 560
#define WROOT2 592
#define WREL3 1104
#define BREL3 3152
#define WROOT3 3216
#define WRELMU 5264
#define BRELMU 9360
#define WROOTMU 9424
#define WRELLV 13520
#define BRELLV 17616
#define WROOTLV 17680
#define GNW 21776
#define GNB 21840
#define GNMS 21904

__device__ __forceinline__ float b2f(u16 u) {
  union { u32 i; float f; } cv; cv.i = ((u32)u) << 16; return cv.f;
}
__device__ __forceinline__ u16 f2b(float f) {
  union { bf16 b; u16 u; } cv; cv.b = __float2bfloat16(f); return cv.u;
}
__device__ __forceinline__ float loadF(const void* p, size_t i, int isbf) {
  if (isbf) return b2f(((const u16*)p)[i]);
  return ((const float*)p)[i];
}
__device__ __forceinline__ int loadI(const void* p, size_t i, int is64) {
  if (is64) return (int)(((const long long*)p)[i]);
  return ((const int*)p)[i];
}

__global__ void probe_k(const void* ew, const void* ei, const void* batch,
                        int* __restrict__ flags) {
  if (threadIdx.x != 0 || blockIdx.x != 0) return;
  const u32* u = (const u32*)ew;
  int hits = 0;
  for (int i = 0; i < 64; ++i) {
    u32 b1 = (u[i] >> 8) & 0xFF;
    if (b1 >= 0x30 && b1 <= 0x3F) hits++;
  }
  flags[0] = (hits >= 32) ? 1 : 0;  // floats are bf16
  const int* w = (const int*)ei;
  int nz = 0;
  for (int i = 1; i < 512; i += 2) nz += (w[i] != 0);
  flags[1] = (nz == 0) ? 1 : 0;  // edge_index int64
  const int* b = (const int*)batch;
  int nzb = 0;
  for (int k = 0; k < 64; ++k) nzb += (b[NN - 1 - 2 * k] != 0);
  flags[2] = (nzb == 0) ? 1 : 0;  // batch int64
}

struct WArg { const void* p[18]; int sz[18]; int off[18]; };

__global__ void cvt_weights(WArg a, float* __restrict__ out, const int* __restrict__ flg) {
  int fb = flg[0];
  int b = blockIdx.x;
  const void* src = a.p[b];
  float* dst = out + a.off[b];
  int n = a.sz[b];
  for (int i = threadIdx.x; i < n; i += blockDim.x) dst[i] = loadF(src, i, fb);
}

// pack weights into MFMA B-fragment order (+ bias vectors), per layer
__global__ void pack_w(const float* __restrict__ wb, u16* __restrict__ wp2,
                       u16* __restrict__ wp3, u16* __restrict__ wpF,
                       float* __restrict__ b2, float* __restrict__ b3,
                       float* __restrict__ bF) {
  int L = blockIdx.x;
  int K = (L == 0) ? 32 : (L == 1) ? 64 : 128;
  int COUT = K;
  int KS = K / 32;
  u16* wp = (L == 0) ? wp2 : (L == 1) ? wp3 : wpF;
  int total = K * COUT;
  for (int idx = threadIdx.x; idx < total; idx += blockDim.x) {
    int j = idx & 7;
    int l = (idx >> 3) & 63;
    int rest = idx >> 9;
    int s = rest % KS;
    int t = rest / KS;
    int k = s * 32 + (l >> 4) * 8 + j;
    int c = t * 16 + (l & 15);
    float v;
    if (L == 0) {
      v = (k < 16) ? wb[WREL2 + k * 32 + c] : wb[WROOT2 + (k - 16) * 32 + c];
    } else if (L == 1) {
      v = (k < 32) ? wb[WREL3 + k * 64 + c] : wb[WROOT3 + (k - 32) * 64 + c];
    } else {
      int cc = c & 63;
      int base;
      if (k < 64) base = (c < 64) ? WRELMU : WRELLV;
      else base = (c < 64) ? WROOTMU : WROOTLV;
      int kk = (k < 64) ? k : (k - 64);
      v = wb[base + kk * 64 + cc];
    }
    wp[idx] = f2b(v);
  }
  for (int c = threadIdx.x; c < COUT; c += blockDim.x) {
    if (L == 0) b2[c] = wb[BREL2 + c];
    else if (L == 1) b3[c] = wb[BREL3 + c];
    else bF[c] = (c < 64) ? wb[BRELMU + c] : wb[BRELLV + (c - 64)];
  }
}

__global__ void seg_offsets(const void* __restrict__ batch, int* __restrict__ goffs,
                            const int* __restrict__ flg) {
  int f64 = flg[2];
  int g = blockIdx.x * blockDim.x + threadIdx.x;
  if (g > GG) return;
  int lo = 0, hi = NN;
  while (lo < hi) {
    int mid = (lo + hi) >> 1;
    if (loadI(batch, mid, f64) < g) lo = mid + 1; else hi = mid;
  }
  goffs[g] = lo;
}

// ---------------- CSR build pass A: radix-stage (R9 binA3, counts removed) ----------------
// Per 4096-edge block: LDS hist over 489 buckets -> prefix -> reserve contiguous
// global runs (one atomic per bucket per block) -> rank+stage sorted in LDS ->
// stream out coalesced runs (~8.4 entries avg).
__global__ __launch_bounds__(256) void binA3(
    const void* __restrict__ ei, const void* __restrict__ ew,
    int* __restrict__ gbcnt, u64* __restrict__ gbucket,
    const int* __restrict__ flg) {
  __shared__ u64 st[BCHUNK];
  __shared__ int hist[512];
  __shared__ int pref[512];
  __shared__ int cur[512];
  __shared__ int gpos[512];
  __shared__ int pairs[256];
  int fi = flg[1], fb = flg[0];
  int t = threadIdx.x;
  int base = blockIdx.x * BCHUNK;
  int cn = EE - base;
  if (cn > BCHUNK) cn = BCHUNK;
  if (cn <= 0) return;
  for (int i = t; i < 512; i += 256) hist[i] = 0;
  __syncthreads();
  // phase 1: load edges, LDS-bucket histogram, payload stays in regs
  u64 pay[16];
  int bkt[16];
#pragma unroll
  for (int k = 0; k < 16; ++k) {
    int idx = k * 256 + t;
    bkt[k] = -1;
    if (idx < cn) {
      int e = base + idx;
      int s = loadI(ei, e, fi);
      int d = loadI(ei, (size_t)EE + e, fi);
      float w = loadF(ew, e, fb);
      int b = d >> 10;
      pay[k] = (u64)((u32)s | ((u32)(d & 1023) << 19)) | ((u64)__float_as_uint(w) << 32);
      bkt[k] = b;
      atomicAdd(&hist[b], 1);
    }
  }
  __syncthreads();
  // phase 2: exclusive prefix over 512 (2/thread) + global run reservation
  int h0 = hist[2 * t], h1 = hist[2 * t + 1];
  pairs[t] = h0 + h1;
  __syncthreads();
  for (int off = 1; off < 256; off <<= 1) {
    int v = pairs[t];
    int vv = (t >= off) ? pairs[t - off] : 0;
    __syncthreads();
    pairs[t] = v + vv;
    __syncthreads();
  }
  int excl = (t > 0) ? pairs[t - 1] : 0;
  pref[2 * t] = excl;
  pref[2 * t + 1] = excl + h0;
  cur[2 * t] = excl;
  cur[2 * t + 1] = excl + h0;
  gpos[2 * t] = (2 * t < NB_SCAN && h0 > 0) ? atomicAdd(&gbcnt[2 * t], h0) : 0;
  gpos[2 * t + 1] = (2 * t + 1 < NB_SCAN && h1 > 0) ? atomicAdd(&gbcnt[2 * t + 1], h1) : 0;
  __syncthreads();
  // phase 3: rank and stage sorted payload in LDS
#pragma unroll
  for (int k = 0; k < 16; ++k) {
    if (bkt[k] >= 0) {
      int slot = atomicAdd(&cur[bkt[k]], 1);
      st[slot] = pay[k];
    }
  }
  __syncthreads();
  // phase 4: stream out; consecutive staged entries -> consecutive global addrs
  for (int i = t; i < cn; i += 256) {
    int lo = 0, hi = NB_SCAN - 1;
    while (lo < hi) {
      int mid = (lo + hi + 1) >> 1;
      if (pref[mid] <= i) lo = mid; else hi = mid - 1;
    }
    int b = lo;
    int posg = gpos[b] + (i - pref[b]);
    if (posg < GCAP) gbucket[(size_t)b * GCAP + posg] = st[i];
  }
}

// scan 489 bucket totals -> exclusive bases
__global__ void scanG(const int* __restrict__ gbcnt, int* __restrict__ gbase) {
  __shared__ int lds[512];
  int t = threadIdx.x;
  int c = (t < NB_SCAN) ? gbcnt[t] : 0;
  if (c > GCAP) c = GCAP;
  lds[t] = c;
  __syncthreads();
  for (int off = 1; off < 512; off <<= 1) {
    int x = lds[t];
    int xx = (t >= off) ? lds[t - off] : 0;
    __syncthreads();
    lds[t] = x + xx;
    __syncthreads();
  }
  if (t < NB_SCAN) gbase[t] = lds[t] - c;  // exclusive
}

// ---------------- CSR build pass B: per-bucket counting sort + offs + coalesced cw ----------------
__global__ __launch_bounds__(256) void sortB4(
    const u64* __restrict__ gbucket, const int* __restrict__ gbcnt,
    const int* __restrict__ gbase, int* __restrict__ offs, int2* __restrict__ cw) {
  __shared__ u64 sorted[CAPB];
  __shared__ int lcnt[1024];
  __shared__ int lcur[1024];
  __shared__ int pscan[256];
  __shared__ int stot;
  int b = blockIdx.x, tid = threadIdx.x;
  int r0 = b << 10;
  int cnt = gbcnt[b];
  if (cnt > GCAP) cnt = GCAP;
  int base = gbase[b];
  for (int i = tid; i < 1024; i += 256) lcnt[i] = 0;
  __syncthreads();
  // phase 1: count per dst-offset
  for (int i = tid; i < cnt; i += 256) {
    u32 p = (u32)gbucket[(size_t)b * GCAP + i];
    atomicAdd(&lcnt[p >> 19], 1);
  }
  __syncthreads();
  // phase 2: exclusive prefix of 1024 counters -> lcur
  int t4 = tid * 4;
  int s0 = lcnt[t4], s1 = lcnt[t4 + 1], s2 = lcnt[t4 + 2], s3 = lcnt[t4 + 3];
  int tsum = s0 + s1 + s2 + s3;
  pscan[tid] = tsum;
  __syncthreads();
  for (int off = 1; off < 256; off <<= 1) {
    int v = pscan[tid];
    int vv = (tid >= off) ? pscan[tid - off] : 0;
    __syncthreads();
    pscan[tid] = v + vv;
    __syncthreads();
  }
  int excl = (tid > 0) ? pscan[tid - 1] : 0;
  lcur[t4] = excl;
  lcur[t4 + 1] = excl + s0;
  lcur[t4 + 2] = excl + s0 + s1;
  lcur[t4 + 3] = excl + s0 + s1 + s2;
  if (tid == 255) stot = pscan[255];
  __syncthreads();
  // write offs (node starts) from pristine lcur; also covers offs[NN] in last bucket
  for (int i = tid; i < 1024; i += 256) {
    int idx = r0 + i;
    if (idx <= NN) offs[idx] = base + lcur[i];
  }
  int total = stot;
  bool stage = (total <= CAPB);
  __syncthreads();
  // phase 3: rank + place
  for (int i = tid; i < cnt; i += 256) {
    u64 pay = gbucket[(size_t)b * GCAP + i];
    u32 p = (u32)pay;
    int pos = atomicAdd(&lcur[p >> 19], 1);
    if (stage) sorted[pos] = pay;
    else cw[(size_t)base + pos] = make_int2((int)(p & 0x7FFFF), (int)(pay >> 32));
  }
  __syncthreads();
  // phase 4: coalesced stream out
  if (stage) {
    for (int i = tid; i < total; i += 256) {
      u64 pay = sorted[i];
      u32 p = (u32)pay;
      cw[(size_t)base + i] = make_int2((int)(p & 0x7FFFF), (int)(pay >> 32));
    }
  }
}

// ---------------- conv1 (fused agg + transform, C_in=1 -> 16) ----------------
__global__ void conv1_k(const void* __restrict__ x, const int2* __restrict__ cw,
                        const int* __restrict__ offs, const float* __restrict__ wb,
                        u16* __restrict__ h1, const int* __restrict__ flg) {
  int fb = flg[0];
  int n = blockIdx.x * blockDim.x + threadIdx.x;
  if (n >= NN) return;
  float acc = 0.f;
  int j1 = offs[n + 1];
  for (int j = offs[n]; j < j1; ++j) {
    int2 p = cw[j];
    acc += __int_as_float(p.y) * loadF(x, p.x, fb);
  }
  float xx = loadF(x, n, fb);
  u32 pk[8];
#pragma unroll
  for (int p = 0; p < 8; ++p) {
    float v0 = fmaxf(acc * wb[WREL1 + 2 * p] + wb[BREL1 + 2 * p] + xx * wb[WROOT1 + 2 * p], 0.f);
    float v1 = fmaxf(acc * wb[WREL1 + 2 * p + 1] + wb[BREL1 + 2 * p + 1] + xx * wb[WROOT1 + 2 * p + 1], 0.f);
    pk[p] = (u32)f2b(v0) | ((u32)f2b(v1) << 16);
  }
  uint4* dst = (uint4*)(h1 + (size_t)n * 16);
  dst[0] = make_uint4(pk[0], pk[1], pk[2], pk[3]);
  dst[1] = make_uint4(pk[4], pk[5], pk[6], pk[7]);
}

// ---------------- fused gather + MFMA node transform, 2-tile pipelined (R8 static) ----------------
template <int K, int COUT, bool RELU, bool FINAL>
__global__ __launch_bounds__(256) void fused_conv(
    const u16* __restrict__ hin, const int2* __restrict__ cw,
    const int* __restrict__ offs, const u16* __restrict__ wpack,
    const float* __restrict__ bias, void* __restrict__ outp,
    const int* __restrict__ flg) {
  constexpr int KS = K / 32, CT = COUT / 16, CIN = K / 2;
  constexpr int AS = CIN / 32;               // pure-agg slices
  constexpr bool MIX = (CIN % 32) == 16;     // mixed slice exists (conv2 only)
  constexpr int GA = AS + (MIX ? 1 : 0);
  constexpr int ST_LD = COUT + 8;            // staging row stride (u16), bank-skewed
  __shared__ u16 wl[K * COUT];
  __shared__ float bl[COUT];
  __shared__ u16 stbuf[FINAL ? 4 : 4 * 16 * ST_LD];
  int tid = threadIdx.x;
  for (int i = tid; i < K * COUT / 8; i += 256)
    ((uint4*)wl)[i] = ((const uint4*)wpack)[i];
  for (int i = tid; i < COUT; i += 256) bl[i] = bias[i];
  __syncthreads();
  int fb = FINAL ? flg[0] : 1;
  int lane = tid & 63, wave = tid >> 6;
  int q = lane & 15, kgrp = lane >> 4;
  u16* st = FINAL ? stbuf : (stbuf + wave * 16 * ST_LD);
  const int ntiles = NN / 16;
  const int gstride = gridDim.x * 4;
  for (int t0 = blockIdx.x * 4 + wave; t0 < ntiles; t0 += 2 * gstride) {
    int t1 = t0 + gstride;
    bool has1 = (t1 < ntiles);
    int nA = t0 * 16 + q;
    int nB = has1 ? (t1 * 16 + q) : nA;
    int jbA = offs[nA], jeA = offs[nA + 1];
    int jbB = 0, jeB = 0;
    if (has1) { jbB = offs[nB]; jeB = offs[nB + 1]; }
    float gacc[2][GA][8];
#pragma unroll
    for (int tt = 0; tt < 2; ++tt)
#pragma unroll
      for (int s = 0; s < GA; ++s)
#pragma unroll
        for (int jj = 0; jj < 8; ++jj) gacc[tt][s][jj] = 0.f;
    int lA = jeA - jbA, lB = jeB - jbB;
    int iters = max((lA + 1) >> 1, (lB + 1) >> 1);
    for (int it = 0; it < iters; ++it) {
      int2 pp[4];
      float ww[4];
      int j0 = jbA + 2 * it, j1 = j0 + 1;
      int j2 = jbB + 2 * it, j3 = j2 + 1;
      int jc0 = j0 < EE ? j0 : EE - 1;
      int jc1 = j1 < EE ? j1 : EE - 1;
      int jc2 = j2 < EE ? j2 : EE - 1;
      int jc3 = j3 < EE ? j3 : EE - 1;
      pp[0] = cw[jc0]; pp[1] = cw[jc1]; pp[2] = cw[jc2]; pp[3] = cw[jc3];
      ww[0] = (j0 < jeA) ? __int_as_float(pp[0].y) : 0.f;
      ww[1] = (j1 < jeA) ? __int_as_float(pp[1].y) : 0.f;
      ww[2] = (j2 < jeB) ? __int_as_float(pp[2].y) : 0.f;
      ww[3] = (j3 < jeB) ? __int_as_float(pp[3].y) : 0.f;
      s16x8 vv[4][GA];
#pragma unroll
      for (int sl = 0; sl < 4; ++sl) {
        const u16* rr = hin + (size_t)pp[sl].x * CIN;
#pragma unroll
        for (int s = 0; s < AS; ++s)
          vv[sl][s] = *(const s16x8*)(rr + s * 32 + kgrp * 8);
        if (MIX && kgrp < 2)
          vv[sl][AS] = *(const s16x8*)(rr + kgrp * 8);
      }
#pragma unroll
      for (int sl = 0; sl < 4; ++sl) {
#pragma unroll
        for (int s = 0; s < AS; ++s)
#pragma unroll
          for (int jj = 0; jj < 8; ++jj)
            gacc[sl >> 1][s][jj] += ww[sl] * b2f((u16)vv[sl][s][jj]);
        if (MIX && kgrp < 2)
#pragma unroll
          for (int jj = 0; jj < 8; ++jj)
            gacc[sl >> 1][AS][jj] += ww[sl] * b2f((u16)vv[sl][AS][jj]);
      }
    }
#pragma unroll
    for (int tt = 0; tt < 2; ++tt) {
      if (tt == 1 && !has1) break;
      int n0 = (tt == 0 ? t0 : t1) * 16;
      int n = n0 + q;
      s16x8 a[KS];
#pragma unroll
      for (int s = 0; s < KS; ++s) {
        if (s < AS) {
          s16x8 t;
#pragma unroll
          for (int jj = 0; jj < 8; ++jj) t[jj] = (short)f2b(gacc[tt][s][jj]);
          a[s] = t;
        } else if (MIX && s == AS) {
          if (kgrp < 2) {
            s16x8 t;
#pragma unroll
            for (int jj = 0; jj < 8; ++jj) t[jj] = (short)f2b(gacc[tt][AS][jj]);
            a[s] = t;
          } else {
            a[s] = *(const s16x8*)(hin + (size_t)n * CIN + (kgrp * 8 - 16));
          }
        } else {
          a[s] = *(const s16x8*)(hin + (size_t)n * CIN + (s * 32 + kgrp * 8 - CIN));
        }
      }
      f32x4 acc[CT];
#pragma unroll
      for (int t = 0; t < CT; ++t) {
        float bv = bl[t * 16 + q];
        acc[t] = (f32x4){bv, bv, bv, bv};
      }
#pragma unroll
      for (int s = 0; s < KS; ++s) {
#pragma unroll
        for (int t = 0; t < CT; ++t) {
          s16x8 b = *(const s16x8*)(wl + ((size_t)(t * KS + s) * 64 + lane) * 8);
          acc[t] = __builtin_amdgcn_mfma_f32_16x16x32_bf16(a[s], b, acc[t], 0, 0, 0);
        }
      }
      if (!FINAL) {
#pragma unroll
        for (int t = 0; t < CT; ++t) {
          int cc = t * 16 + q;
#pragma unroll
          for (int r = 0; r < 4; ++r) {
            float v = acc[t][r];
            if (RELU) v = fmaxf(v, 0.f);
            st[(kgrp * 4 + r) * ST_LD + cc] = f2b(v);
          }
        }
        constexpr int LPR = COUT / 8;
        constexpr int PASSES = 16 * LPR / 64;
        u16* out = (u16*)outp;
#pragma unroll
        for (int p = 0; p < PASSES; ++p) {
          int idx = p * 64 + lane;
          int row = idx / LPR, seg = idx % LPR;
          *(uint4*)(out + (size_t)(n0 + row) * COUT + seg * 8) =
              *(const uint4*)(st + row * ST_LD + seg * 8);
        }
      } else {
#pragma unroll
        for (int t = 0; t < CT; ++t) {
          int c = t * 16 + q;
#pragma unroll
          for (int r = 0; r < 4; ++r) {
            int nn = n0 + kgrp * 4 + r;
            float v = acc[t][r];
            size_t addr = (t < 4) ? ((size_t)nn * 64 + c)
                                  : ((size_t)NN * 64 + (size_t)nn * 64 + (c - 64));
            if (fb) ((u16*)outp)[addr] = f2b(v);
            else ((float*)outp)[addr] = v;
          }
        }
      }
    }
  }
}

// ---------------- GraphNorm, 2-pass (sum+sumsq fused), H3 -> H3n ----------------
__global__ void graphnorm2(const u16* __restrict__ h, u16* __restrict__ hn,
                           const int* __restrict__ goffs, const float* __restrict__ wb) {
  __shared__ float red[1024];
  __shared__ float red2[1024];
  __shared__ float Ax[64];
  __shared__ float Bx[64];
  int g = blockIdx.x;
  int s = goffs[g], e = goffs[g + 1];
  int len = e - s;
  if (len <= 0) return;
  long base = (long)s * 64, end = (long)e * 64;
  int t = threadIdx.x;
  int c = t & 63;

  float ls = 0.f, lq = 0.f;
  for (long i = base + t; i < end; i += 1024) {
    float v = b2f(h[i]);
    ls += v; lq += v * v;
  }
  red[t] = ls; red2[t] = lq;
  __syncthreads();
  if (t < 64) {
    float S = 0.f, Q = 0.f;
#pragma unroll
    for (int j = 0; j < 16; ++j) { S += red[t + 64 * j]; Q += red2[t + 64 * j]; }
    float mean = S / (float)len;
    float ex2 = Q / (float)len;
    float mms = mean * wb[GNMS + t];
    float var = ex2 - 2.f * mms * mean + mms * mms;
    float a = wb[GNW + t] * rsqrtf(var + 1e-5f);
    Ax[t] = a;
    Bx[t] = wb[GNB + t] - mms * a;
  }
  __syncthreads();
  for (long i = base + t; i < end; i += 1024)
    hn[i] = f2b(b2f(h[i]) * Ax[c] + Bx[c]);
}

extern "C" void kernel_launch(void* const* d_in, const int* in_sizes, int n_in,
                              void* d_out, int out_size, void* d_ws, size_t ws_size,
                              hipStream_t stream) {
  const void* x = d_in[0];
  const void* ei = d_in[1];
  const void* ew = d_in[2];
  const void* batch = d_in[3];

  char* ws = (char*)d_ws;
  // Layout (bytes):
  //  H3      [0, 64e6)        bf16 N*64 (conv3 output, pre-norm)
  //  cw      [64e6, 80e6)     int2 E (col, wgt-bits), dst-sorted CSR payload
  //  offs    [80e6, +2.000004e6)
  //  bsum(unused) wb [87.1e6, +88KB)  goffs [87.25e6, +1028B)  flags [87.3e6, +16B)
  //  wp2     [87.35e6, +2KB)  wp3 [87.4e6, +8KB)  wpF [87.45e6, +32KB)
  //  bias2   [87.5e6) bias3 [87.51e6) biasF [87.52e6)
  //  gbcnt   [87.53e6, +1956B)  gbase [87.56e6, +1956B)
  //  C = [88e6, 256e6), time-shared:
  //    gbucket u64 489*8192 @C+0   [88e6, 120.05e6)  (CSR build only)
  //    h1   bf16 N*16 @C+0     [88e6, 104e6)   (written by conv1, after CSR)
  //    h2   bf16 N*32 @C+32e6  [120e6, 152e6)  (written by conv2, after CSR)
  //    H3n  bf16 N*64 @C+96e6  [184e6, 248e6)  (normalized)
  u16* H3 = (u16*)(ws);
  int2* cw = (int2*)(ws + 64000000);
  int* offs = (int*)(ws + 80000000);
  float* wb = (float*)(ws + 87100000);
  int* goffs = (int*)(ws + 87250000);
  int* flags = (int*)(ws + 87300000);
  u16* wp2 = (u16*)(ws + 87350000);
  u16* wp3 = (u16*)(ws + 87400000);
  u16* wpF = (u16*)(ws + 87450000);
  float* bias2 = (float*)(ws + 87500000);
  float* bias3 = (float*)(ws + 87510000);
  float* biasF = (float*)(ws + 87520000);
  int* gbcnt = (int*)(ws + 87530000);
  int* gbase = (int*)(ws + 87560000);
  char* C = ws + 88000000;
  u64* gbucket = (u64*)(C);
  u16* h1 = (u16*)(C);
  u16* h2 = (u16*)(C + 32000000);
  u16* H3n = (u16*)(C + 96000000);

  WArg wa;
  const int wsz[18] = {16, 16, 16, 512, 32, 512, 2048, 64, 2048,
                       4096, 64, 4096, 4096, 64, 4096, 64, 64, 64};
  const int woff[18] = {WREL1, BREL1, WROOT1, WREL2, BREL2, WROOT2,
                        WREL3, BREL3, WROOT3, WRELMU, BRELMU, WROOTMU,
                        WRELLV, BRELLV, WROOTLV, GNW, GNB, GNMS};
  for (int i = 0; i < 18; ++i) { wa.p[i] = d_in[4 + i]; wa.sz[i] = wsz[i]; wa.off[i] = woff[i]; }

  probe_k<<<1, 64, 0, stream>>>(ew, ei, batch, flags);
  cvt_weights<<<18, 256, 0, stream>>>(wa, wb, flags);
  pack_w<<<3, 256, 0, stream>>>(wb, wp2, wp3, wpF, bias2, bias3, biasF);
  seg_offsets<<<2, 256, 0, stream>>>(batch, goffs, flags);

  // CSR build: radix-stage -> bucket-base scan -> per-bucket counting sort (+offs)
  hipMemsetAsync(gbcnt, 0, (size_t)NB_SCAN * sizeof(int), stream);
  binA3<<<(EE + BCHUNK - 1) / BCHUNK, 256, 0, stream>>>(ei, ew, gbcnt, gbucket, flags);
  scanG<<<1, 512, 0, stream>>>(gbcnt, gbase);
  sortB4<<<NB_SCAN, 256, 0, stream>>>(gbucket, gbcnt, gbase, offs, cw);

  // conv1: 1 -> 16
  conv1_k<<<(NN + 255) / 256, 256, 0, stream>>>(x, cw, offs, wb, h1, flags);

  // conv2: 16 -> 32 (K=32), gather fused
  fused_conv<32, 32, true, false><<<2048, 256, 0, stream>>>(
      h1, cw, offs, wp2, bias2, h2, flags);

  // conv3: 32 -> 64 (K=64), gather fused
  fused_conv<64, 64, true, false><<<2048, 256, 0, stream>>>(
      h2, cw, offs, wp3, bias3, H3, flags);

  // GraphNorm: H3 -> H3n (2-pass)
  graphnorm2<<<GG, 1024, 0, stream>>>(H3, H3n, goffs, wb);

  // mu + logvar (K=128, COUT=128), gather fused, reads normalized H3n
  fused_conv<128, 128, false, true><<<2048, 256, 0, stream>>>(
      H3n, cw, offs, wpF, biasF, d_out, flags);
}